// Round 2
// baseline (60.832 us; speedup 1.0000x reference)
//
#include <hip/hip_runtime.h>
#include <math.h>
#include <float.h>

#define OFFSET_X 1.0f
#define OFFSET_Y 0.3f
#define T_HORIZON 5.0f

__global__ __launch_bounds__(256) void BackupBarrierCBF_kernel(
    const float* __restrict__ data, float* __restrict__ out, int n)
{
    int i = blockIdx.x * blockDim.x + threadIdx.x;
    if (i >= n) return;

    const float* p = data + (size_t)i * 15;
    float ex0  = p[0],  ey0 = p[1],  eyaw = p[2],  ev = p[3];
    float ax0  = p[4],  ay0 = p[5],  ayaw = p[6],  av = p[7];
    float eL   = p[8],  eW  = p[9];
    float aL   = p[11], aW  = p[12];
    float dt   = p[14];

    int n_t = (int)(T_HORIZON / dt + 0.5f);

    float ce = __cosf(eyaw), se = __sinf(eyaw);
    float ca = __cosf(ayaw), sa = __sinf(ayaw);

    // Per-step relative velocity (agent - ego), rotated into ego frame, scaled by dt.
    float dvx = av * ca - ev * ce;
    float dvy = av * sa - ev * se;
    float dX  = ( dvx * ce + dvy * se) * dt;
    float dY  = (-dvx * se + dvy * ce) * dt;

    float rx0 = ax0 - ex0;
    float ry0 = ay0 - ey0;

    float hx = 0.5f * eL + OFFSET_X;
    float hy = 0.5f * eW + OFFSET_Y;
    float hcx = 0.5f * aL;
    float hcy = 0.5f * aW;

    // Agent box corners in ego frame at t=0 (sx = {+,+,-,-}, sy = {+,-,+,-}).
    float X0, X1, X2, X3, Y0, Y1, Y2, Y3;
    {
        float axc = hcx * ca, axs = hcx * sa;
        float ayc = hcy * ca, ays = hcy * sa;
        // corner k: cx = +-hcx, cy = +-hcy
        float wx0 = rx0 + axc - ays, wy0 = ry0 + axs + ayc;  // (+,+)
        float wx1 = rx0 + axc + ays, wy1 = ry0 + axs - ayc;  // (+,-)
        float wx2 = rx0 - axc - ays, wy2 = ry0 - axs + ayc;  // (-,+)
        float wx3 = rx0 - axc + ays, wy3 = ry0 - axs - ayc;  // (-,-)
        X0 =  wx0 * ce + wy0 * se;  Y0 = -wx0 * se + wy0 * ce;
        X1 =  wx1 * ce + wy1 * se;  Y1 = -wx1 * se + wy1 * ce;
        X2 =  wx2 * ce + wy2 * se;  Y2 = -wx2 * se + wy2 * ce;
        X3 =  wx3 * ce + wy3 * se;  Y3 = -wx3 * se + wy3 * ce;
    }

    // Independent per-corner running minima (no cross-corner serial chain).
    float m0 = FLT_MAX, m1 = FLT_MAX, m2 = FLT_MAX, m3 = FLT_MAX;
    for (int t = 0; t < n_t; ++t) {
        X0 += dX; Y0 += dY;
        X1 += dX; Y1 += dY;
        X2 += dX; Y2 += dY;
        X3 += dX; Y3 += dY;
        m0 = fminf(m0, fmaxf(fabsf(X0) - hx, fabsf(Y0) - hy));
        m1 = fminf(m1, fmaxf(fabsf(X1) - hx, fabsf(Y1) - hy));
        m2 = fminf(m2, fmaxf(fabsf(X2) - hx, fabsf(Y2) - hy));
        m3 = fminf(m3, fmaxf(fabsf(X3) - hx, fabsf(Y3) - hy));
    }
    float m = fminf(fminf(m0, m1), fminf(m2, m3));

    // (sigmoid(m/5) - 0.5) * 10
    float s = 1.0f / (1.0f + __expf(-m * 0.2f));
    out[i] = (s - 0.5f) * 10.0f;
}

extern "C" void kernel_launch(void* const* d_in, const int* in_sizes, int n_in,
                              void* d_out, int out_size, void* d_ws, size_t ws_size,
                              hipStream_t stream) {
    const float* data = (const float*)d_in[0];
    float* out = (float*)d_out;
    int n = out_size;  // B*A = 4096*32 = 131072
    int block = 256;
    int grid = (n + block - 1) / block;
    BackupBarrierCBF_kernel<<<grid, block, 0, stream>>>(data, out, n);
}